// Round 11
// baseline (136.513 us; speedup 1.0000x reference)
//
#include <hip/hip_runtime.h>
#include <hip/hip_bf16.h>
#include <math.h>
#include <stddef.h>

// Problem shape: z [4,64,16,32,32] fp32, embedding [1024,64] fp32
#define CH     64
#define DHWC   16384
#define NTOK   65536
#define KCODES 1024
#define OUT_ELEMS 4194304

typedef _Float16 f16;
typedef f16  f16x8  __attribute__((ext_vector_type(8)));
typedef float fltx4 __attribute__((ext_vector_type(4)));

struct Ws {
  // ---- zeroed header (memset range = offsetof(Ws, e_norm)) ----
  double sum_z2, sum_e2, loss_sum;
  int    ticket, pad0;            // (unused; layout kept)
  float  sum_z[CH];               // f32 atomics (from writer blocks)
  double sum_e[CH];
  int    counts[KCODES];
  // ---- filled by eprep ----
  float  e_norm[KCODES];
  float  accI[KCODES + 48];       // -e_norm/2 (+pad)
  // codebook pre-swizzled into MFMA B-fragment order (verified layout)
  alignas(16) f16 e_frag[(64 + 2) * 2 * 64 * 8];
  // z pre-converted to f16, transposed to [tok][ch] (8 MB): gemm A-fragments
  // become single dwordx4 loads. Bitwise same RNE cvt as the inline path.
  alignas(16) f16 zt16[(size_t)NTOK * CH];
  // ---- per-half exact winners (gemm -> writer) ----
  float          hd[2 * NTOK];
  unsigned short hk[2 * NTOK];
};

// ---- eprep: blocks 0-15 codebook prep (verified); blocks 16-271: z->f16
// transpose into zt16 (coalesced reads lane=token; 16B row writes).
__global__ void vq_eprep(const float* __restrict__ z,
                         const float* __restrict__ emb, Ws* __restrict__ ws) {
  __shared__ float tile[64][68];
  __shared__ float red[256];
  const int tid = threadIdx.x;
  if (blockIdx.x >= 16) {
    // ---- z transpose: 256 blocks x 256 tokens ----
    const int t  = blockIdx.x - 16;
    const int n0t = t * 256;
    const int bb = n0t >> 14;
    const int ss = (n0t & 16383) + tid;
    const float* zb = z + (size_t)bb * (CH * DHWC) + ss;
    f16* dst = ws->zt16 + (size_t)(n0t + tid) * CH;
    #pragma unroll
    for (int g = 0; g < 8; ++g) {
      f16 buf[8];
      #pragma unroll
      for (int j = 0; j < 8; ++j)
        buf[j] = (f16)zb[(size_t)(g * 8 + j) * DHWC];
      *(f16x8*)(dst + g * 8) = *(f16x8*)buf;
    }
    return;
  }
  const int r = tid >> 2;                 // code row within block (0..63)
  const int q = tid & 3;                  // quarter of the 64-channel row
  const int k = blockIdx.x * 64 + r;
  const float4* src = (const float4*)(emb + (size_t)k * CH + q * 16);
  float4 a = src[0], b = src[1], c = src[2], d = src[3];
  float4* dst = (float4*)(&tile[r][q * 16]);
  dst[0] = a; dst[1] = b; dst[2] = c; dst[3] = d;
  float s2 = 0.f;
  s2 = fmaf(a.x,a.x,s2); s2 = fmaf(a.y,a.y,s2); s2 = fmaf(a.z,a.z,s2); s2 = fmaf(a.w,a.w,s2);
  s2 = fmaf(b.x,b.x,s2); s2 = fmaf(b.y,b.y,s2); s2 = fmaf(b.z,b.z,s2); s2 = fmaf(b.w,b.w,s2);
  s2 = fmaf(c.x,c.x,s2); s2 = fmaf(c.y,c.y,s2); s2 = fmaf(c.z,c.z,s2); s2 = fmaf(c.w,c.w,s2);
  s2 = fmaf(d.x,d.x,s2); s2 = fmaf(d.y,d.y,s2); s2 = fmaf(d.z,d.z,s2); s2 = fmaf(d.w,d.w,s2);
  // verified-exact row norm (absmax 0.0)
  float t1 = s2 + __shfl_xor(s2, 1);
  float t2 = t1 + __shfl_xor(t1, 2);
  if (q == 0) { ws->e_norm[k] = t2; ws->accI[k] = -0.5f * t2; }
  // pre-swizzled B-fragment write (verified)
  {
    float vals[16] = {a.x,a.y,a.z,a.w, b.x,b.y,b.z,b.w,
                      c.x,c.y,c.z,c.w, d.x,d.y,d.z,d.w};
    const int ct  = blockIdx.x * 4 + (r >> 4);
    const int nn  = r & 15;
    const int b01 = q >> 1;
    const int qd0 = (q & 1) * 2;
    f16 h8a[8], h8b[8];
    #pragma unroll
    for (int u = 0; u < 8; ++u) { h8a[u] = (f16)vals[u]; h8b[u] = (f16)vals[8 + u]; }
    f16x8* fr = (f16x8*)ws->e_frag;
    fr[(ct * 2 + b01) * 64 + (qd0 + 0) * 16 + nn] = *(f16x8*)h8a;
    fr[(ct * 2 + b01) * 64 + (qd0 + 1) * 16 + nn] = *(f16x8*)h8b;
  }
  red[tid] = s2;
  __syncthreads();
  for (int off = 128; off > 0; off >>= 1) {
    if (tid < off) red[tid] += red[tid + off];
    __syncthreads();
  }
  if (tid == 0) atomicAdd(&ws->sum_e2, (double)red[0]);
  if (tid < CH) {
    float cs = 0.f;
    #pragma unroll 8
    for (int rr = 0; rr < 64; ++rr) cs += tile[rr][tid];
    atomicAdd(&ws->sum_e[tid], (double)cs);
  }
}

// ---- phase 1+2: half-codebook in LDS, 2 blocks/CU (R9/R10-verified) -----
// R11: A-fragments = single dwordx4 loads from zt16 (no scalar loads/cvt);
// explicit depth-1 B prefetch; setprio around the MFMA cluster.
__global__ __launch_bounds__(512, 4)
void vq_gemm(const float* __restrict__ z, const float* __restrict__ emb,
             Ws* __restrict__ ws) {
  // LDS 69632 B: [0,65536) efr; [65536,67584) accl; [67584,69632) candm
  __shared__ char smem[69632];
  f16x8*    efr   = (f16x8*)smem;
  float*    accl  = (float*)(smem + 65536);
  unsigned* candm = (unsigned*)(smem + 67584);

  const int tid = threadIdx.x;
  const int h   = blockIdx.x & 1;          // K-half (co-resident pair shares z)
  const int tg  = blockIdx.x >> 1;         // token group (256 tokens)
  const int n0  = tg * 256;
  const int b   = n0 >> 14;
  const int s0  = n0 & 16383;
  const float* zbase = z + (size_t)b * (CH * DHWC) + s0;

  // stage half-B (64 KB) + accI-half into LDS (coalesced 16B/lane)
  {
    const f16x8* gsrc = ((const f16x8*)ws->e_frag) + h * 4096;
    #pragma unroll
    for (int r = 0; r < 8; ++r)
      efr[r * 512 + tid] = gsrc[r * 512 + tid];
    accl[tid] = ws->accI[h * 512 + tid];
  }

  const int lane = tid & 63;
  const int w    = tid >> 6;           // wave 0..7
  const int qg   = w & 1;              // 256-code group within the half
  const int tw   = w >> 1;             // token quarter (64 tokens)
  const int nn   = lane & 15;          // MFMA column (code class)
  const int quad = lane >> 4;

  // A fragments: ONE dwordx4 load each from zt16 (identical f16 bits):
  // Ah[mt][ks] = zt16[tok=n0+tw*64+mt*16+nn][ch group ks*4+quad]
  const f16x8* ztp = ((const f16x8*)ws->zt16) + (size_t)n0 * 8;
  f16x8 Ah[4][2];
  #pragma unroll
  for (int mt = 0; mt < 4; ++mt) {
    const int row = tw * 64 + mt * 16 + nn;
    Ah[mt][0] = ztp[row * 8 + quad];
    Ah[mt][1] = ztp[row * 8 + 4 + quad];
  }
  __syncthreads();                     // efr/accl staged

  // packed-key top-2 per (token-slot, class):
  // key = (score bits & ~1023) | (1023 - k): distinct keys, max = best,
  // k decodable from low 10 bits; exact distances restored by recheck.
  float m1[16], m2[16];
  #pragma unroll
  for (int u = 0; u < 16; ++u) { m1[u] = -3.4e38f; m2[u] = -3.4e38f; }

  const f16x8* Bp = efr + lane;
  unsigned orb = (unsigned)(1023 - h * 512 - qg * 256 - nn);
  int ctl = qg * 16;
  f16x8 B0 = Bp[(ctl * 2 + 0) * 64];
  f16x8 B1 = Bp[(ctl * 2 + 1) * 64];
  float ai = accl[ctl * 16 + nn];
  #pragma unroll 2
  for (int it = 0; it < 16; ++it) {
    // depth-1 prefetch (last iter overruns into staged neighbor/pad: unused)
    f16x8 nB0 = Bp[((ctl + 1) * 2 + 0) * 64];
    f16x8 nB1 = Bp[((ctl + 1) * 2 + 1) * 64];
    const float nai = accl[(ctl + 1) * 16 + nn];
    __builtin_amdgcn_s_setprio(1);
    #pragma unroll
    for (int mt = 0; mt < 4; ++mt) {
      fltx4 a = {ai, ai, ai, ai};
      a = __builtin_amdgcn_mfma_f32_16x16x32_f16(Ah[mt][0], B0, a, 0, 0, 0);
      a = __builtin_amdgcn_mfma_f32_16x16x32_f16(Ah[mt][1], B1, a, 0, 0, 0);
      #pragma unroll
      for (int r = 0; r < 4; ++r) {
        const int u = mt * 4 + r;
        float key = __uint_as_float((__float_as_uint(a[r]) & 0xFFFFFC00u) | orb);
        m2[u] = fmaxf(m2[u], fminf(m1[u], key));
        m1[u] = fmaxf(m1[u], key);
      }
    }
    __builtin_amdgcn_s_setprio(0);
    orb -= 16;
    ++ctl;
    B0 = nB0; B1 = nB1; ai = nai;
  }

  // in-wave tournament across the 16 nn-lanes: exact top-2 of the group.
  // merge of sorted pairs: m1'=max(m1,o1); m2'=max(min(m1,o1),max(m2,o2)).
  #pragma unroll
  for (int s = 1; s <= 8; s <<= 1) {
    #pragma unroll
    for (int u = 0; u < 16; ++u) {
      float o1 = __shfl_xor(m1[u], s);
      float o2 = __shfl_xor(m2[u], s);
      float lo = fminf(m1[u], o1);
      m1[u] = fmaxf(m1[u], o1);
      m2[u] = fmaxf(lo, fmaxf(m2[u], o2));
    }
  }
  if (nn == 0) {
    #pragma unroll
    for (int mt = 0; mt < 4; ++mt)
      #pragma unroll
      for (int r = 0; r < 4; ++r) {
        const int u = mt * 4 + r;
        const int tok = tw * 64 + mt * 16 + quad * 4 + r;  // C/D row (verified)
        unsigned kA = 1023u - (__float_as_uint(m1[u]) & 1023u);
        unsigned kB = 1023u - (__float_as_uint(m2[u]) & 1023u);
        candm[tok * 2 + qg] = kA | (kB << 16);
      }
  }
  __syncthreads();

  // exact dual recheck (verified chain): 2 threads/token, group j each;
  // in-wave (d asc, k asc) merge over the 2 groups -> per-half winner.
  {
    const int t = tid >> 1, j = tid & 1;
    const unsigned cd = candm[t * 2 + j];
    const int ka = (int)(cd & 0xffffu), kb = (int)(cd >> 16);
    const float4* ea4 = (const float4*)(emb + (size_t)ka * CH);
    const float4* eb4 = (const float4*)(emb + (size_t)kb * CH);
    const float* zt = zbase + t;
    float znorm = 0.f, da = 0.f, db = 0.f;
    #pragma unroll 4
    for (int c4 = 0; c4 < 16; ++c4) {
      float4 ev = ea4[c4];
      float4 fv = eb4[c4];
      float v0 = zt[(size_t)(4*c4+0) * DHWC];
      float v1 = zt[(size_t)(4*c4+1) * DHWC];
      float v2 = zt[(size_t)(4*c4+2) * DHWC];
      float v3 = zt[(size_t)(4*c4+3) * DHWC];
      znorm = fmaf(v0, v0, znorm); znorm = fmaf(v1, v1, znorm);
      znorm = fmaf(v2, v2, znorm); znorm = fmaf(v3, v3, znorm);
      da = fmaf(v0, ev.x, da); da = fmaf(v1, ev.y, da);
      da = fmaf(v2, ev.z, da); da = fmaf(v3, ev.w, da);
      db = fmaf(v0, fv.x, db); db = fmaf(v1, fv.y, db);
      db = fmaf(v2, fv.z, db); db = fmaf(v3, fv.w, db);
    }
    float dda = fmaf(-2.f, da, znorm + ws->e_norm[ka]);
    float ddb = fmaf(-2.f, db, znorm + ws->e_norm[kb]);
    bool pa = (dda < ddb) || (dda == ddb && ka < kb);
    float dd = pa ? dda : ddb;
    int   kk = pa ? ka : kb;
    float od = __shfl_xor(dd, 1); int ok = __shfl_xor(kk, 1);
    if (od < dd || (od == dd && ok < kk)) { dd = od; kk = ok; }
    if (j == 0) {
      ws->hd[h * NTOK + n0 + t] = dd;
      ws->hk[h * NTOK + n0 + t] = (unsigned short)kk;
    }
  }
}

// ---- phase 3: 2-way merge + output + loss + counts + z-sums (R9 form) ---
// grid 512 x 512; block = HALF a (b,c) plane: 2 blocks/CU.
__global__ __launch_bounds__(512, 4)
void vq_writer(const float* __restrict__ z, const float* __restrict__ emb,
               float* __restrict__ out, Ws* __restrict__ ws) {
  __shared__ float ecol[KCODES];     // column c of emb (4 KB)
  __shared__ int   hist[KCODES];     // LDS histogram (c==0 blocks only)
  __shared__ float sh[24];
  const int bid = blockIdx.x;
  const int p    = bid >> 1;         // plane: b*64 + c
  const int half = bid & 1;          // half-plane
  const int tid = threadIdx.x;
  const int b = p >> 6, c = p & 63;
  const bool docnt = (c == 0);
  ecol[tid]       = emb[(size_t)tid * CH + c];
  ecol[tid + 512] = emb[(size_t)(tid + 512) * CH + c];
  if (docnt) { hist[tid] = 0; hist[tid + 512] = 0; }
  __syncthreads();

  const size_t base = (size_t)p * DHWC + half * 8192;
  const float4* zp = (const float4*)(z + base);
  float4* op = (float4*)(out + base);
  const int nbase = b * 16384 + half * 8192;
  const float*          hd0 = ws->hd + nbase;
  const float*          hd1 = ws->hd + NTOK + nbase;
  const unsigned short* hk0 = ws->hk + nbase;
  const unsigned short* hk1 = ws->hk + NTOK + nbase;
  float lp = 0.f, ss = 0.f, ss2 = 0.f;
  #pragma unroll
  for (int i = tid; i < 2048; i += 512) {          // 4 iterations
    float4 v  = zp[i];
    float4 d0 = *(const float4*)(hd0 + 4 * i);
    float4 d1 = *(const float4*)(hd1 + 4 * i);
    ushort4 ka = *(const ushort4*)(hk0 + 4 * i);
    ushort4 kb = *(const ushort4*)(hk1 + 4 * i);
    int w0 = (d0.x < d1.x || (d0.x == d1.x && ka.x < kb.x)) ? ka.x : kb.x;
    int w1 = (d0.y < d1.y || (d0.y == d1.y && ka.y < kb.y)) ? ka.y : kb.y;
    int w2 = (d0.z < d1.z || (d0.z == d1.z && ka.z < kb.z)) ? ka.z : kb.z;
    int w3 = (d0.w < d1.w || (d0.w == d1.w && ka.w < kb.w)) ? ka.w : kb.w;
    float q0 = ecol[w0], q1 = ecol[w1], q2 = ecol[w2], q3 = ecol[w3];
    float e0 = q0 - v.x, e1 = q1 - v.y, e2 = q2 - v.z, e3 = q3 - v.w;
    float4 o; o.x = v.x + e0; o.y = v.y + e1; o.z = v.z + e2; o.w = v.w + e3;
    op[i] = o;
    lp = fmaf(e0, e0, lp); lp = fmaf(e1, e1, lp);
    lp = fmaf(e2, e2, lp); lp = fmaf(e3, e3, lp);
    ss += v.x + v.y + v.z + v.w;
    ss2 = fmaf(v.x, v.x, ss2); ss2 = fmaf(v.y, v.y, ss2);
    ss2 = fmaf(v.z, v.z, ss2); ss2 = fmaf(v.w, v.w, ss2);
    if (docnt) {
      atomicAdd(&hist[w0], 1);
      atomicAdd(&hist[w1], 1);
      atomicAdd(&hist[w2], 1);
      atomicAdd(&hist[w3], 1);
    }
  }
  #pragma unroll
  for (int off = 32; off > 0; off >>= 1) {
    lp  += __shfl_down(lp, off);
    ss  += __shfl_down(ss, off);
    ss2 += __shfl_down(ss2, off);
  }
  if ((tid & 63) == 0) {
    sh[tid >> 6] = lp; sh[8 + (tid >> 6)] = ss; sh[16 + (tid >> 6)] = ss2;
  }
  __syncthreads();
  if (docnt) {
    int h0 = hist[tid];
    if (h0) atomicAdd(&ws->counts[tid], h0);
    int h1 = hist[tid + 512];
    if (h1) atomicAdd(&ws->counts[tid + 512], h1);
  }
  if (tid == 0) {
    float t = 0.f, tz = 0.f, tz2 = 0.f;
    #pragma unroll
    for (int i = 0; i < 8; ++i) { t += sh[i]; tz += sh[8+i]; tz2 += sh[16+i]; }
    atomicAdd(&ws->loss_sum, (double)t);
    atomicAdd(&ws->sum_z[c], tz);
    atomicAdd(&ws->sum_z2, (double)tz2);
  }
}

// ---- final: scalars (R0-verified, separate kernel = free ordering) ------
__global__ void vq_final(Ws* __restrict__ ws, float* __restrict__ out_scalars) {
  const int tid = threadIdx.x;
  float p = (float)ws->counts[tid] * (1.0f / 65536.0f);
  float term = p * logf(p + 1e-10f);
  __shared__ float sh[1024];
  sh[tid] = term;
  __syncthreads();
  for (int off = 512; off > 0; off >>= 1) {
    if (tid < off) sh[tid] += sh[tid + off];
    __syncthreads();
  }
  if (tid == 0) {
    float perp = expf(-sh[0]);
    double m = ws->loss_sum / (double)OUT_ELEMS;
    float mf = (float)m;
    float loss = mf + 0.25f * mf;
    double sdot = 0.0;
    #pragma unroll
    for (int c = 0; c < CH; ++c) sdot += (double)ws->sum_z[c] * ws->sum_e[c];
    double md = ws->sum_z2 / (double)NTOK + ws->sum_e2 / (double)KCODES
              - 2.0 * sdot / ((double)NTOK * (double)KCODES);
    out_scalars[0] = loss;
    out_scalars[1] = perp;
    out_scalars[2] = (float)md;
  }
}

extern "C" void kernel_launch(void* const* d_in, const int* in_sizes, int n_in,
                              void* d_out, int out_size, void* d_ws, size_t ws_size,
                              hipStream_t stream) {
  const float* z   = (const float*)d_in[0];
  const float* emb = (const float*)d_in[1];
  float* out = (float*)d_out;
  Ws* ws = (Ws*)d_ws;

  hipMemsetAsync(d_ws, 0, offsetof(Ws, e_norm), stream);
  vq_eprep <<<272, 256, 0, stream>>>(z, emb, ws);
  vq_gemm  <<<512, 512, 0, stream>>>(z, emb, ws);
  vq_writer<<<512, 512, 0, stream>>>(z, emb, out, ws);
  vq_final <<<1,   1024, 0, stream>>>(ws, out + OUT_ELEMS);
}

// Round 13
// 117.852 us; speedup vs baseline: 1.1583x; 1.1583x over previous
//
#include <hip/hip_runtime.h>
#include <hip/hip_bf16.h>
#include <math.h>
#include <stddef.h>

// Problem shape: z [4,64,16,32,32] fp32, embedding [1024,64] fp32
#define CH     64
#define DHWC   16384
#define NTOK   65536
#define KCODES 1024
#define OUT_ELEMS 4194304

typedef _Float16 f16;
typedef f16  f16x8  __attribute__((ext_vector_type(8)));
typedef float fltx4 __attribute__((ext_vector_type(4)));

struct Ws {
  // ---- zeroed header (memset range = offsetof(Ws, e_norm)) ----
  double sum_z2, sum_e2, loss_sum, pad;
  float  sum_z[CH];               // f32 atomics (from writer blocks)
  double sum_e[CH];
  int    counts[KCODES];
  // ---- filled by eprep ----
  float  e_norm[KCODES];
  float  accI[KCODES + 48];       // -e_norm/2 (+pad)
  // codebook pre-swizzled into MFMA B-fragment order (verified layout)
  alignas(16) f16 e_frag[(64 + 2) * 2 * 64 * 8];
  // ---- per-half exact winners (gemm -> writer) ----
  float          hd[2 * NTOK];
  unsigned short hk[2 * NTOK];
};

// ---- eprep: e_norm (exact chain) + e-sums + fragments (verified) --------
__global__ void vq_eprep(const float* __restrict__ emb, Ws* __restrict__ ws) {
  __shared__ float tile[64][68];
  __shared__ float red[256];
  const int tid = threadIdx.x;
  const int r = tid >> 2;                 // code row within block (0..63)
  const int q = tid & 3;                  // quarter of the 64-channel row
  const int k = blockIdx.x * 64 + r;
  const float4* src = (const float4*)(emb + (size_t)k * CH + q * 16);
  float4 a = src[0], b = src[1], c = src[2], d = src[3];
  float4* dst = (float4*)(&tile[r][q * 16]);
  dst[0] = a; dst[1] = b; dst[2] = c; dst[3] = d;
  float s2 = 0.f;
  s2 = fmaf(a.x,a.x,s2); s2 = fmaf(a.y,a.y,s2); s2 = fmaf(a.z,a.z,s2); s2 = fmaf(a.w,a.w,s2);
  s2 = fmaf(b.x,b.x,s2); s2 = fmaf(b.y,b.y,s2); s2 = fmaf(b.z,b.z,s2); s2 = fmaf(b.w,b.w,s2);
  s2 = fmaf(c.x,c.x,s2); s2 = fmaf(c.y,c.y,s2); s2 = fmaf(c.z,c.z,s2); s2 = fmaf(c.w,c.w,s2);
  s2 = fmaf(d.x,d.x,s2); s2 = fmaf(d.y,d.y,s2); s2 = fmaf(d.z,d.z,s2); s2 = fmaf(d.w,d.w,s2);
  // verified-exact row norm (absmax 0.0)
  float t1 = s2 + __shfl_xor(s2, 1);
  float t2 = t1 + __shfl_xor(t1, 2);
  if (q == 0) { ws->e_norm[k] = t2; ws->accI[k] = -0.5f * t2; }
  // pre-swizzled B-fragment write (verified)
  {
    float vals[16] = {a.x,a.y,a.z,a.w, b.x,b.y,b.z,b.w,
                      c.x,c.y,c.z,c.w, d.x,d.y,d.z,d.w};
    const int ct  = blockIdx.x * 4 + (r >> 4);
    const int nn  = r & 15;
    const int b01 = q >> 1;
    const int qd0 = (q & 1) * 2;
    f16 h8a[8], h8b[8];
    #pragma unroll
    for (int u = 0; u < 8; ++u) { h8a[u] = (f16)vals[u]; h8b[u] = (f16)vals[8 + u]; }
    f16x8* fr = (f16x8*)ws->e_frag;
    fr[(ct * 2 + b01) * 64 + (qd0 + 0) * 16 + nn] = *(f16x8*)h8a;
    fr[(ct * 2 + b01) * 64 + (qd0 + 1) * 16 + nn] = *(f16x8*)h8b;
  }
  red[tid] = s2;
  __syncthreads();
  for (int off = 128; off > 0; off >>= 1) {
    if (tid < off) red[tid] += red[tid + off];
    __syncthreads();
  }
  if (tid == 0) atomicAdd(&ws->sum_e2, (double)red[0]);
  if (tid < CH) {
    float cs = 0.f;
    #pragma unroll 8
    for (int rr = 0; rr < 64; ++rr) cs += tile[rr][tid];
    atomicAdd(&ws->sum_e[tid], (double)cs);
  }
}

// ---- phase 1+2: B-in-LDS MFMA + in-wave tournament + exact recheck ------
// Best-measured configuration (116.97 us total): grid 512 = 256 tg x 2
// halves; 512 threads; 68.6 KB LDS -> 2 blocks/CU (16 waves/CU), the two
// co-resident blocks overlapping each other's phases. A-fragments loaded
// directly from global z (hidden under the LDS staging barrier);
// per-class top-2 (verified packed keys) merged to exact per-half top-2
// by a 4-step shfl_xor tournament (no cand array, no LDS bank
// conflicts). Recheck: 2 threads/token, 1 candidate each.
__global__ __launch_bounds__(512, 4)
void vq_gemm(const float* __restrict__ z, const float* __restrict__ emb,
             Ws* __restrict__ ws) {
  // LDS 68608 B: [0,65536) ef; [65536,67584) accl; [67584,68608) candm
  __shared__ char smem[68608];
  f16x8*    efr   = (f16x8*)smem;
  float*    accl  = (float*)(smem + 65536);
  unsigned* candm = (unsigned*)(smem + 67584);

  const int tid = threadIdx.x;
  const int h   = blockIdx.x & 1;          // K-half
  const int tg  = blockIdx.x >> 1;         // token group (256 tokens)
  const int n0  = tg * 256;
  const int b   = n0 >> 14;
  const int s0  = n0 & 16383;
  const float* zbase = z + (size_t)b * (CH * DHWC) + s0;

  // stage B-half + accI-half into LDS (coalesced 16B/lane, 8 rounds)
  {
    const f16x8* gsrc = ((const f16x8*)ws->e_frag) + h * 4096;
    #pragma unroll
    for (int r = 0; r < 8; ++r)
      efr[r * 512 + tid] = gsrc[r * 512 + tid];
    accl[tid] = ws->accI[h * 512 + tid];
  }

  const int lane = tid & 63;
  const int w    = tid >> 6;           // wave: tokens [w*32, w*32+32)
  const int nn   = lane & 15;          // MFMA column (code class)
  const int quad = lane >> 4;

  // A fragments DIRECT from global (same f16 RNE cvt as the staged path):
  // Ah[mt][ks][j] = (f16) z[ch=ks*32+quad*8+j][tok=w*32+mt*16+nn]
  f16x8 Ah[2][2];
  #pragma unroll
  for (int mt = 0; mt < 2; ++mt) {
    const int row = w * 32 + mt * 16 + nn;
    #pragma unroll
    for (int ks = 0; ks < 2; ++ks) {
      f16 tmp[8];
      #pragma unroll
      for (int j = 0; j < 8; ++j)
        tmp[j] = (f16)zbase[(size_t)(ks * 32 + quad * 8 + j) * DHWC + row];
      Ah[mt][ks] = *(f16x8*)tmp;
    }
  }
  __syncthreads();                     // ef/accl staged

  // packed-key top-2 per (token-slot, class):
  // key = (score bits & ~1023) | (1023 - k): distinct keys, max = best,
  // k decodable from low 10 bits; exact distances restored by recheck.
  float m1[8], m2[8];
  #pragma unroll
  for (int u = 0; u < 8; ++u) { m1[u] = -3.4e38f; m2[u] = -3.4e38f; }

  const f16x8* Bp = efr + lane;
  unsigned orb = (unsigned)(1023 - h * 512 - nn);
  #pragma unroll 4
  for (int itp = 0; itp < 16; ++itp) {     // ct-pair per iteration
    const int c0 = itp * 2;
    f16x8 B0a = Bp[(c0 * 2 + 0) * 64];
    f16x8 B1a = Bp[(c0 * 2 + 1) * 64];
    f16x8 B0b = Bp[(c0 * 2 + 2) * 64];
    f16x8 B1b = Bp[(c0 * 2 + 3) * 64];
    const float aia = accl[c0 * 16 + nn];
    const float aib = accl[c0 * 16 + 16 + nn];
    fltx4 acc0a = {aia, aia, aia, aia};
    acc0a = __builtin_amdgcn_mfma_f32_16x16x32_f16(Ah[0][0], B0a, acc0a, 0, 0, 0);
    acc0a = __builtin_amdgcn_mfma_f32_16x16x32_f16(Ah[0][1], B1a, acc0a, 0, 0, 0);
    fltx4 acc1a = {aia, aia, aia, aia};
    acc1a = __builtin_amdgcn_mfma_f32_16x16x32_f16(Ah[1][0], B0a, acc1a, 0, 0, 0);
    acc1a = __builtin_amdgcn_mfma_f32_16x16x32_f16(Ah[1][1], B1a, acc1a, 0, 0, 0);
    fltx4 acc0b = {aib, aib, aib, aib};
    acc0b = __builtin_amdgcn_mfma_f32_16x16x32_f16(Ah[0][0], B0b, acc0b, 0, 0, 0);
    acc0b = __builtin_amdgcn_mfma_f32_16x16x32_f16(Ah[0][1], B1b, acc0b, 0, 0, 0);
    fltx4 acc1b = {aib, aib, aib, aib};
    acc1b = __builtin_amdgcn_mfma_f32_16x16x32_f16(Ah[1][0], B0b, acc1b, 0, 0, 0);
    acc1b = __builtin_amdgcn_mfma_f32_16x16x32_f16(Ah[1][1], B1b, acc1b, 0, 0, 0);
    const unsigned oA = orb, oB = orb - 16;
    #pragma unroll
    for (int r = 0; r < 4; ++r) {
      float ka = __uint_as_float((__float_as_uint(acc0a[r]) & 0xFFFFFC00u) | oA);
      float kb = __uint_as_float((__float_as_uint(acc0b[r]) & 0xFFFFFC00u) | oB);
      float hi = fmaxf(ka, kb), lo = fminf(ka, kb);
      m2[r] = fmaxf(fmaxf(fminf(m1[r], hi), lo), m2[r]);
      m1[r] = fmaxf(m1[r], hi);
      float kc = __uint_as_float((__float_as_uint(acc1a[r]) & 0xFFFFFC00u) | oA);
      float kd = __uint_as_float((__float_as_uint(acc1b[r]) & 0xFFFFFC00u) | oB);
      float hi2 = fmaxf(kc, kd), lo2 = fminf(kc, kd);
      m2[4+r] = fmaxf(fmaxf(fminf(m1[4+r], hi2), lo2), m2[4+r]);
      m1[4+r] = fmaxf(m1[4+r], hi2);
    }
    orb -= 32;
  }

  // in-wave tournament across the 16 nn-lanes: exact top-2 of the half.
  // merge of sorted pairs: m1'=max(m1,o1); m2'=max(min(m1,o1),max(m2,o2)).
  #pragma unroll
  for (int s = 1; s <= 8; s <<= 1) {
    #pragma unroll
    for (int u = 0; u < 8; ++u) {
      float o1 = __shfl_xor(m1[u], s);
      float o2 = __shfl_xor(m2[u], s);
      float lo = fminf(m1[u], o1);
      m1[u] = fmaxf(m1[u], o1);
      m2[u] = fmaxf(lo, fmaxf(m2[u], o2));
    }
  }
  if (nn == 0) {
    #pragma unroll
    for (int mt = 0; mt < 2; ++mt)
      #pragma unroll
      for (int r = 0; r < 4; ++r) {
        const int u = mt * 4 + r;
        const int tok = w * 32 + mt * 16 + quad * 4 + r;  // C/D row (verified)
        unsigned kA = 1023u - (__float_as_uint(m1[u]) & 1023u);
        unsigned kB = 1023u - (__float_as_uint(m2[u]) & 1023u);
        candm[tok] = kA | (kB << 16);
      }
  }
  __syncthreads();

  // exact recheck (verified chain): 2 threads/token, 1 candidate each
  {
    const int tok = tid >> 1, j = tid & 1;
    const unsigned cd = candm[tok];
    const int kc = (int)((j ? (cd >> 16) : cd) & 0xffffu);
    const float4* ep = (const float4*)(emb + (size_t)kc * CH);
    const float* zt = zbase + tok;
    float znorm = 0.f, dpr = 0.f;
    #pragma unroll 4
    for (int c4 = 0; c4 < 16; ++c4) {
      float4 ev = ep[c4];
      float v0 = zt[(size_t)(4*c4+0) * DHWC];
      float v1 = zt[(size_t)(4*c4+1) * DHWC];
      float v2 = zt[(size_t)(4*c4+2) * DHWC];
      float v3 = zt[(size_t)(4*c4+3) * DHWC];
      znorm = fmaf(v0, v0, znorm); znorm = fmaf(v1, v1, znorm);
      znorm = fmaf(v2, v2, znorm); znorm = fmaf(v3, v3, znorm);
      dpr = fmaf(v0, ev.x, dpr); dpr = fmaf(v1, ev.y, dpr);
      dpr = fmaf(v2, ev.z, dpr); dpr = fmaf(v3, ev.w, dpr);
    }
    float dd = fmaf(-2.f, dpr, znorm + ws->e_norm[kc]);
    int   kk = kc;
    float od = __shfl_xor(dd, 1); int ok = __shfl_xor(kk, 1);
    if (od < dd || (od == dd && ok < kk)) { dd = od; kk = ok; }
    if (j == 0) {
      ws->hd[h * NTOK + n0 + tok] = dd;
      ws->hk[h * NTOK + n0 + tok] = (unsigned short)kk;
    }
  }
}

// ---- phase 3: combine halves + output + loss + counts + z-sums ----------
// grid 256 x 1024; block = ONE (b,c) plane (R0-verified core).
__global__ __launch_bounds__(1024, 4)
void vq_writer(const float* __restrict__ z, const float* __restrict__ emb,
               float* __restrict__ out, Ws* __restrict__ ws) {
  __shared__ float ecol[KCODES];     // column c of emb (4 KB)
  __shared__ int   hist[KCODES];     // LDS histogram (c==0 blocks only)
  __shared__ float sh[48];
  const int p   = blockIdx.x;        // plane: b*64 + c
  const int tid = threadIdx.x;
  const int b = p >> 6, c = p & 63;
  const bool docnt = (c == 0);
  ecol[tid] = emb[(size_t)tid * CH + c];
  if (docnt) hist[tid] = 0;
  __syncthreads();

  const size_t base = (size_t)p * DHWC;
  const float4* zp = (const float4*)(z + base);
  float4* op = (float4*)(out + base);
  const int nbase = b * 16384;
  const float*          hd0 = ws->hd + nbase;
  const float*          hd1 = ws->hd + NTOK + nbase;
  const unsigned short* hk0 = ws->hk + nbase;
  const unsigned short* hk1 = ws->hk + NTOK + nbase;
  float lp = 0.f, ss = 0.f, ss2 = 0.f;
  #pragma unroll
  for (int i = tid; i < 4096; i += 1024) {         // 4 iterations
    float4 v  = zp[i];
    float4 d0 = *(const float4*)(hd0 + 4 * i);
    float4 d1 = *(const float4*)(hd1 + 4 * i);
    ushort4 ka = *(const ushort4*)(hk0 + 4 * i);
    ushort4 kb = *(const ushort4*)(hk1 + 4 * i);
    int w0 = (d0.x < d1.x || (d0.x == d1.x && ka.x < kb.x)) ? ka.x : kb.x;
    int w1 = (d0.y < d1.y || (d0.y == d1.y && ka.y < kb.y)) ? ka.y : kb.y;
    int w2 = (d0.z < d1.z || (d0.z == d1.z && ka.z < kb.z)) ? ka.z : kb.z;
    int w3 = (d0.w < d1.w || (d0.w == d1.w && ka.w < kb.w)) ? ka.w : kb.w;
    float q0 = ecol[w0], q1 = ecol[w1], q2 = ecol[w2], q3 = ecol[w3];
    float e0 = q0 - v.x, e1 = q1 - v.y, e2 = q2 - v.z, e3 = q3 - v.w;
    float4 o; o.x = v.x + e0; o.y = v.y + e1; o.z = v.z + e2; o.w = v.w + e3;
    op[i] = o;
    lp = fmaf(e0, e0, lp); lp = fmaf(e1, e1, lp);
    lp = fmaf(e2, e2, lp); lp = fmaf(e3, e3, lp);
    ss += v.x + v.y + v.z + v.w;
    ss2 = fmaf(v.x, v.x, ss2); ss2 = fmaf(v.y, v.y, ss2);
    ss2 = fmaf(v.z, v.z, ss2); ss2 = fmaf(v.w, v.w, ss2);
    if (docnt) {
      atomicAdd(&hist[w0], 1);
      atomicAdd(&hist[w1], 1);
      atomicAdd(&hist[w2], 1);
      atomicAdd(&hist[w3], 1);
    }
  }
  #pragma unroll
  for (int off = 32; off > 0; off >>= 1) {
    lp  += __shfl_down(lp, off);
    ss  += __shfl_down(ss, off);
    ss2 += __shfl_down(ss2, off);
  }
  if ((tid & 63) == 0) {
    sh[tid >> 6] = lp; sh[16 + (tid >> 6)] = ss; sh[32 + (tid >> 6)] = ss2;
  }
  __syncthreads();
  if (docnt) {
    int h2 = hist[tid];
    if (h2) atomicAdd(&ws->counts[tid], h2);
  }
  if (tid == 0) {
    float t = 0.f, tz = 0.f, tz2 = 0.f;
    #pragma unroll
    for (int i = 0; i < 16; ++i) { t += sh[i]; tz += sh[16+i]; tz2 += sh[32+i]; }
    atomicAdd(&ws->loss_sum, (double)t);
    atomicAdd(&ws->sum_z[c], tz);
    atomicAdd(&ws->sum_z2, (double)tz2);
  }
}

// ---- final: scalars (R0-verified) ---------------------------------------
__global__ void vq_final(Ws* __restrict__ ws, float* __restrict__ out_scalars) {
  const int tid = threadIdx.x;
  float p = (float)ws->counts[tid] * (1.0f / 65536.0f);
  float term = p * logf(p + 1e-10f);
  __shared__ float sh[1024];
  sh[tid] = term;
  __syncthreads();
  for (int off = 512; off > 0; off >>= 1) {
    if (tid < off) sh[tid] += sh[tid + off];
    __syncthreads();
  }
  if (tid == 0) {
    float perp = expf(-sh[0]);
    double m = ws->loss_sum / (double)OUT_ELEMS;
    float mf = (float)m;
    float loss = mf + 0.25f * mf;
    double sdot = 0.0;
    #pragma unroll
    for (int c = 0; c < CH; ++c) sdot += (double)ws->sum_z[c] * ws->sum_e[c];
    double md = ws->sum_z2 / (double)NTOK + ws->sum_e2 / (double)KCODES
              - 2.0 * sdot / ((double)NTOK * (double)KCODES);
    out_scalars[0] = loss;
    out_scalars[1] = perp;
    out_scalars[2] = (float)md;
  }
}

extern "C" void kernel_launch(void* const* d_in, const int* in_sizes, int n_in,
                              void* d_out, int out_size, void* d_ws, size_t ws_size,
                              hipStream_t stream) {
  const float* z   = (const float*)d_in[0];
  const float* emb = (const float*)d_in[1];
  float* out = (float*)d_out;
  Ws* ws = (Ws*)d_ws;

  hipMemsetAsync(d_ws, 0, offsetof(Ws, e_norm), stream);
  vq_eprep <<<16,  256,  0, stream>>>(emb, ws);
  vq_gemm  <<<512, 512,  0, stream>>>(z, emb, ws);
  vq_writer<<<256, 1024, 0, stream>>>(z, emb, out, ws);
  vq_final <<<1,   1024, 0, stream>>>(ws, out + OUT_ELEMS);
}